// Round 1
// baseline (334.801 us; speedup 1.0000x reference)
//
#include <hip/hip_runtime.h>

// Problem constants (from reference): B=16, L=4096, H=768, fp32.
#define BB 16
#define LL 4096
#define HH 768          // floats per row
#define H4 (HH / 4)     // 192 float4 per row

// start[b][j] = first p with seg[b][p] >= j  (lower_bound), for j in [0, L].
// Thread idx = b*(L+1)+p. Thread p writes start[j]=p for j in (seg[p-1], seg[p]]
// (with seg[-1] := -1, seg[L] := L). Union of these intervals is exactly [0, L],
// so every entry is written exactly once — no zeroing of ws required.
__global__ __launch_bounds__(256) void boundaries_kernel(
    const int* __restrict__ seg, int* __restrict__ start) {
    int idx = blockIdx.x * blockDim.x + threadIdx.x;
    if (idx >= BB * (LL + 1)) return;
    int b = idx / (LL + 1);
    int p = idx - b * (LL + 1);
    const int* s = seg + (size_t)b * LL;
    int cur  = (p < LL) ? s[p]     : LL;
    int prev = (p > 0)  ? s[p - 1] : -1;
    int* st = start + (size_t)b * (LL + 1);
    for (int j = prev + 1; j <= cur; ++j) st[j] = p;
}

// One wave per output row (b, j). Lane i accumulates float4s at column offsets
// i, i+64, i+128 (covers 192 float4 = 768 floats). Sums x rows [s, e).
// Ranges across consecutive j tile [0, L) monotonically -> coalesced, L2-friendly.
__global__ __launch_bounds__(256) void segsum_kernel(
    const float4* __restrict__ x, const int* __restrict__ start,
    float4* __restrict__ out) {
    int gtid = blockIdx.x * blockDim.x + threadIdx.x;
    int wave = gtid >> 6;          // 0 .. B*L-1
    int lane = gtid & 63;
    int b = wave >> 12;            // / L
    int j = wave & (LL - 1);       // % L

    const int* st = start + (size_t)b * (LL + 1) + j;
    int s = st[0];
    int e = st[1];

    float4 a0 = make_float4(0.f, 0.f, 0.f, 0.f);
    float4 a1 = a0, a2 = a0;

    const float4* xb = x + (size_t)b * LL * H4;
    for (int p = s; p < e; ++p) {
        const float4* row = xb + (size_t)p * H4 + lane;
        float4 v0 = row[0];
        float4 v1 = row[64];
        float4 v2 = row[128];
        a0.x += v0.x; a0.y += v0.y; a0.z += v0.z; a0.w += v0.w;
        a1.x += v1.x; a1.y += v1.y; a1.z += v1.z; a1.w += v1.w;
        a2.x += v2.x; a2.y += v2.y; a2.z += v2.z; a2.w += v2.w;
    }

    float4* orow = out + (size_t)wave * H4 + lane;
    orow[0]   = a0;
    orow[64]  = a1;
    orow[128] = a2;
}

extern "C" void kernel_launch(void* const* d_in, const int* in_sizes, int n_in,
                              void* d_out, int out_size, void* d_ws, size_t ws_size,
                              hipStream_t stream) {
    const float* x   = (const float*)d_in[0];        // (B, L, H) fp32
    const int*   seg = (const int*)d_in[1];          // (B, L) int32, sorted per row
    float* out = (float*)d_out;                      // (B, L, H) fp32
    int* start = (int*)d_ws;                         // B*(L+1) ints = 262 KiB

    // 1) boundary (lower_bound) table
    int nb_threads = BB * (LL + 1);
    boundaries_kernel<<<(nb_threads + 255) / 256, 256, 0, stream>>>(seg, start);

    // 2) per-token gather-sum: B*L waves, 4 waves per 256-thread block
    int nblocks = (BB * LL) / 4;   // 16384
    segsum_kernel<<<nblocks, 256, 0, stream>>>(
        (const float4*)x, start, (float4*)out);
}

// Round 2
// 328.939 us; speedup vs baseline: 1.0178x; 1.0178x over previous
//
#include <hip/hip_runtime.h>

// Problem: per-batch segment_sum over sorted segment ids.
// B=16, L=4096, H=768, fp32. out[b,j,:] = sum_{p: seg[b,p]==j} x[b,p,:].
// Sorted ids => token j's wordpieces are the contiguous range
// [lower_bound(seg_b, j), lower_bound(seg_b, j+1)).
#define BB 16
#define LL 4096
#define H4 192   // 768 floats = 192 float4 per row

// One wave per output token (b, j). The wave computes its own range bounds
// with a 64-ary ballot search over the (L1-resident, 16 KB) sorted seg row:
//   step 1: lane i probes seg[i*64]  -> which 64-block holds the boundary
//   step 2: lanes probe that block   -> exact lower_bound
// Then lane i gather-sums float4 columns {i, i+64, i+128} over rows [s, e)
// and writes the output row (zeros for empty tokens -> poison overwritten).
__global__ __launch_bounds__(256) void segsum_fused_kernel(
    const float4* __restrict__ x, const int* __restrict__ seg,
    float4* __restrict__ out) {
    int gtid = blockIdx.x * blockDim.x + threadIdx.x;
    int wave = gtid >> 6;          // 0 .. B*L-1
    int lane = gtid & 63;
    int b = wave >> 12;            // / L
    int j = wave & (LL - 1);       // % L

    const int* __restrict__ sb = seg + ((size_t)b << 12);

    // step-1 probe (whole row, stride 64) — shared by both bounds
    int v1 = sb[lane << 6];
    unsigned long long ms = __ballot(v1 >= j);       // for lower_bound(j)
    unsigned long long me = __ballot(v1 > j);        // for lower_bound(j+1)

    int s, e;
    if (ms & 1ull) {
        s = 0;                     // seg[0] >= j
    } else {
        int f = ms ? (__ffsll((unsigned long long)ms) - 1) : 64;
        int base = ((f - 1) << 6) + 1;               // search (f-1)*64+1 .. f*64
        int p2 = base + lane;
        int v2 = (p2 < LL) ? sb[p2] : 0x7fffffff;    // seg[L] := +inf
        unsigned long long m2 = __ballot(v2 >= j);   // lane 63 always eligible
        s = base + __ffsll(m2) - 1;
    }
    if (me & 1ull) {
        e = 0;
    } else {
        int f = me ? (__ffsll((unsigned long long)me) - 1) : 64;
        int base = ((f - 1) << 6) + 1;
        int p2 = base + lane;
        int v2 = (p2 < LL) ? sb[p2] : 0x7fffffff;
        unsigned long long m2 = __ballot(v2 > j);
        e = base + __ffsll(m2) - 1;
    }

    float4 a0 = make_float4(0.f, 0.f, 0.f, 0.f);
    float4 a1 = a0, a2 = a0;

    const float4* xb = x + (size_t)b * LL * H4;
    for (int p = s; p < e; ++p) {
        const float4* row = xb + (size_t)p * H4 + lane;
        float4 v0 = row[0];
        float4 vA = row[64];
        float4 vB = row[128];
        a0.x += v0.x; a0.y += v0.y; a0.z += v0.z; a0.w += v0.w;
        a1.x += vA.x; a1.y += vA.y; a1.z += vA.z; a1.w += vA.w;
        a2.x += vB.x; a2.y += vB.y; a2.z += vB.z; a2.w += vB.w;
    }

    float4* orow = out + (size_t)wave * H4 + lane;
    orow[0]   = a0;
    orow[64]  = a1;
    orow[128] = a2;
}

extern "C" void kernel_launch(void* const* d_in, const int* in_sizes, int n_in,
                              void* d_out, int out_size, void* d_ws, size_t ws_size,
                              hipStream_t stream) {
    const float* x   = (const float*)d_in[0];   // (B, L, H) fp32
    const int*   seg = (const int*)d_in[1];     // (B, L) int32, sorted per row
    float* out = (float*)d_out;                 // (B, L, H) fp32
    (void)d_ws; (void)ws_size;

    // B*L waves total, 4 waves per 256-thread block -> 16384 blocks
    int nblocks = (BB * LL) / 4;
    segsum_fused_kernel<<<nblocks, 256, 0, stream>>>(
        (const float4*)x, seg, (float4*)out);
}